// Round 8
// baseline (128.049 us; speedup 1.0000x reference)
//
#include <hip/hip_runtime.h>

// CanadarmJacob: 131072 items. Evidence through R7: dur = 94.1(harness) +
// kernel; kernels stuck at 29.7-31.7us across 4 structures; R5 counters:
// latency-bound (1.1TB/s, VALU 7%, Occ 9.8%). Diagnosis: no intra-wave
// overlap -- every wave eats a full ~900cyc HBM stall per lifetime.
// R8: persistent 1-wave blocks, double-buffered DMA, counted vmcnt(27):
// batch t+1's 27 global_load_lds stay in flight across batch t's compute.
// grid=512 (2 blocks/CU), 4 batches x 64 items per block. Compute algebra
// unchanged (verified absmax 0.0078).

#define IPB 64     // items per batch (= lanes)
#define NB  4      // batches per block
#define NDMA 27    // 21 pose + 6 com global_load_lds per batch (exact)

typedef const __attribute__((address_space(1))) void GAS;
typedef __attribute__((address_space(3))) void LAS;

__global__ __launch_bounds__(64, 1) void canadarm_jacob_kernel(
    const float* __restrict__ com,
    const float* __restrict__ pose,
    const int* __restrict__ bm_ptr,
    float* __restrict__ out)
{
    __shared__ float4 poseL[2][IPB * 21];   // 2 x 21504 B
    __shared__ float4 comL[2][384];         // 2 x 6144 B  (336 live + pad)

    const int lane = threadIdx.x;
    const int base_item = blockIdx.x * (NB * IPB);   // 256 items/block

    // ---- per-lane constant DMA source offsets (batch-invariant) ----
    // pose: slot d = j*64+lane -> item it=d/21, live-idx li=d%21, row r=li/7,
    //       s=li%7, src f4 = it*36 + 9r + (s<2 ? s : s+2)
    int psrc[21];
#pragma unroll
    for (int j = 0; j < 21; ++j) {
        const int d  = j * 64 + lane;
        const int it = d / 21;
        const int li = d - it * 21;
        const int r  = li / 7;
        const int q  = li - r * 7;
        psrc[j] = it * 36 + 9 * r + (q < 2 ? q : q + 2);
    }
    // com: identity f4 copy, 336 live f4 per batch; clamp tail sources
    int csrc[6];
#pragma unroll
    for (int i = 0; i < 6; ++i) {
        const int c = i * 64 + lane;
        csrc[i] = c < 336 ? c : 335;
    }

    const float4* Pb = reinterpret_cast<const float4*>(pose);
    const float4* Cb = reinterpret_cast<const float4*>(com);

    auto ISSUE = [&](int t, int b) {
        // batch base: item0 = base_item + t*IPB
        const float4* P0 = Pb + (size_t)(base_item + t * IPB) * 36;
        const float4* C0 = Cb + (size_t)(base_item + t * IPB) * 21 / 4;  // *84B/16, exact
#pragma unroll
        for (int j = 0; j < 21; ++j)
            __builtin_amdgcn_global_load_lds((GAS*)(P0 + psrc[j]),
                                             (LAS*)(&poseL[b][j * 64]), 16, 0, 0);
#pragma unroll
        for (int i = 0; i < 6; ++i)
            __builtin_amdgcn_global_load_lds((GAS*)(C0 + csrc[i]),
                                             (LAS*)(&comL[b][i * 64]), 16, 0, 0);
    };

    // ---- constants ----
    const float MASS[7] = {105.98f, 105.98f, 314.98f, 279.2f, 105.98f, 105.98f, 243.66f};
    const float SUMM[7] = {1261.76f, 1155.78f, 1049.80f, 734.82f, 455.62f, 349.64f, 243.66f};
    const float SIX[7] = {79.083f, 66.893f, 54.703f, 39.293f, 29.771f, 21.466f, 9.336f};
    const float SIY[7] = {4144.971f, 4132.781f, 4120.591f, 2025.881f, 59.601f, 56.540f, 44.410f};
    const float SIZ[7] = {4131.1016f, 4128.0406f, 4124.9796f, 2021.7896f, 55.5096f, 47.471f, 44.410f};
    const float TM     = 101505.42f;
    const float INV_TM = 1.0f / 101505.42f;
    const float BCZ    = 6.65f * 243.66f / 100243.66f;

    const int bm = bm_ptr[0];

    ISSUE(0, 0);   // prologue

#pragma unroll
    for (int t = 0; t < NB; ++t) {
        const int b = t & 1;

        // drain prior ds_reads before DMA re-targets that buffer (WAR)
        asm volatile("s_waitcnt lgkmcnt(0)" ::: "memory");
        if (t + 1 < NB) {
            ISSUE(t + 1, b ^ 1);
            // wait batch t's 27 DMAs (oldest); batch t+1's 27 stay in flight.
            // (also drains batch t-1's stores -- issued >1 phase ago)
            asm volatile("s_waitcnt vmcnt(27)" ::: "memory");
        } else {
            asm volatile("s_waitcnt vmcnt(0)" ::: "memory");
        }

        // ---- compute batch t (lane = item) ----
        const float4* L = &poseL[b][lane * 21];
        float rot[3][7];
        float tr[3][8];
#pragma unroll
        for (int r = 0; r < 3; ++r) {
            const float4 q0 = L[7 * r + 0];
            const float4 q1 = L[7 * r + 1];
            const float4 q4 = L[7 * r + 2];
            const float4 q5 = L[7 * r + 3];
            const float4 q6 = L[7 * r + 4];
            const float4 q7 = L[7 * r + 5];
            const float4 q8 = L[7 * r + 6];
            rot[r][0] = q4.z;
            rot[r][1] = q0.y;
            rot[r][2] = q5.x;
            rot[r][3] = q5.y;
            rot[r][4] = -q5.z;   // ROT_SIGN[4] = -1
            rot[r][5] = q1.y;
            rot[r][6] = q6.x;
            tr[r][0] = q6.w;
            tr[r][1] = q7.x; tr[r][2] = q7.y; tr[r][3] = q7.z; tr[r][4] = q7.w;
            tr[r][5] = q8.x; tr[r][6] = q8.y; tr[r][7] = q8.z;
        }

        float o[42];

        if (bm) {
            const float* Cf = reinterpret_cast<const float*>(&comL[b][0]) + lane * 21;
            float cm[3][7];
#pragma unroll
            for (int r = 0; r < 3; ++r)
#pragma unroll
                for (int i = 0; i < 7; ++i) cm[r][i] = Cf[r * 7 + i];

            float scx = 0.f, scy = 0.f, scz = 0.f;
#pragma unroll
            for (int i = 0; i < 7; ++i) {
                scx += cm[0][i] * MASS[i];
                scy += cm[1][i] * MASS[i];
                scz += cm[2][i] * MASS[i];
            }
            const float vx = scx * INV_TM;
            const float vy = scy * INV_TM;
            const float vz = scz * INV_TM - BCZ;

            float dp[3][7], jt[3][7];
            float hxx = SIX[0], hyy = SIY[0], hzz = SIZ[0];
            float hxy = 0.f, hxz = 0.f, hyz = 0.f;
#pragma unroll
            for (int i = 0; i < 7; ++i) {
                const float x = cm[0][i] - tr[0][i];
                const float y = cm[1][i] - tr[1][i];
                const float z = cm[2][i] - tr[2][i];
                dp[0][i] = x; dp[1][i] = y; dp[2][i] = z;
                jt[0][i] = rot[1][i] * z - rot[2][i] * y;
                jt[1][i] = rot[2][i] * x - rot[0][i] * z;
                jt[2][i] = rot[0][i] * y - rot[1][i] * x;
                const float m = MASS[i];
                hxx += m * (y * y + z * z);
                hyy += m * (x * x + z * z);
                hzz += m * (x * x + y * y);
                hxy -= m * x * y;
                hxz -= m * x * z;
                hyz -= m * y * z;
            }

            float wx[7], wy[7], wz[7];
            wx[6] = MASS[6] * dp[0][6];
            wy[6] = MASS[6] * dp[1][6];
            wz[6] = MASS[6] * dp[2][6];
#pragma unroll
            for (int k = 5; k >= 0; --k) {
                wx[k] = wx[k + 1] + MASS[k] * dp[0][k];
                wy[k] = wy[k + 1] + MASS[k] * dp[1][k];
                wz[k] = wz[k + 1] + MASS[k] * dp[2][k];
            }

            const float vv = vx * vx + vy * vy + vz * vz;
            const float a  = hxx + TM * (vx * vx - vv);
            const float bb = hxy + TM * (vx * vy);
            const float cc = hxz + TM * (vx * vz);
            const float e  = hyy + TM * (vy * vy - vv);
            const float f  = hyz + TM * (vy * vz);
            const float i9 = hzz + TM * (vz * vz - vv);

            const float c11 = e * i9 - f * f;
            const float c12 = cc * f - bb * i9;
            const float c13 = bb * f - e * cc;
            const float det = a * c11 + bb * c12 + cc * c13;
            const float rdet = 1.0f / det;
            const float i00 = c11 * rdet;
            const float i01 = c12 * rdet;
            const float i02 = c13 * rdet;
            const float i11 = (a * i9 - cc * cc) * rdet;
            const float i12 = (cc * bb - a * f) * rdet;
            const float i22 = (a * e - bb * bb) * rdet;

#pragma unroll
            for (int k = 0; k < 7; ++k) {
                const float ux = wx[k] - SUMM[k] * vx;
                const float uy = wy[k] - SUMM[k] * vy;
                const float uz = wz[k] - SUMM[k] * vz;
                const float jx = jt[0][k], jy = jt[1][k], jz = jt[2][k];
                const float htx = SIX[k] * rot[0][k] + uy * jz - uz * jy;
                const float hty = SIY[k] * rot[1][k] + uz * jx - ux * jz;
                const float htz = SIZ[k] * rot[2][k] + ux * jy - uy * jx;
                const float bx = i00 * htx + i01 * hty + i02 * htz;
                const float by = i01 * htx + i11 * hty + i12 * htz;
                const float bz = i02 * htx + i12 * hty + i22 * htz;
                const float s = SUMM[k] * INV_TM;
                o[0 * 7 + k] = -(s * jx + vy * bz - vz * by);
                o[1 * 7 + k] = -(s * jy + vz * bx - vx * bz);
                o[2 * 7 + k] = -(s * jz + vx * by - vy * bx);
                o[3 * 7 + k] = -bx;
                o[4 * 7 + k] = -by;
                o[5 * 7 + k] = -bz;
            }
        } else {
#pragma unroll
            for (int k = 0; k < 7; ++k) {
                const float dx = tr[0][7] - tr[0][k];
                const float dy = tr[1][7] - tr[1][k];
                const float dz = tr[2][7] - tr[2][k];
                o[0 * 7 + k] = rot[1][k] * dz - rot[2][k] * dy;
                o[1 * 7 + k] = rot[2][k] * dx - rot[0][k] * dz;
                o[2 * 7 + k] = rot[0][k] * dy - rot[1][k] * dx;
                o[3 * 7 + k] = rot[0][k];
                o[4 * 7 + k] = rot[1][k];
                o[5 * 7 + k] = rot[2][k];
            }
        }

        // ---- store batch t: 21 float2 per thread (8B-aligned; proven
        // perf-equivalent to staged stores in R2->R4 A/B) ----
        float2* Ob = reinterpret_cast<float2*>(out + (size_t)(base_item + t * IPB + lane) * 42);
#pragma unroll
        for (int j = 0; j < 21; ++j) Ob[j] = make_float2(o[2 * j], o[2 * j + 1]);
    }
}

extern "C" void kernel_launch(void* const* d_in, const int* in_sizes, int n_in,
                              void* d_out, int out_size, void* d_ws, size_t ws_size,
                              hipStream_t stream) {
    const float* com  = (const float*)d_in[0];   // (512,256,3,7)  f32
    const float* pose = (const float*)d_in[1];   // (512,256,4,4,9) f32
    const int*   bm   = (const int*)d_in[2];     // scalar
    float* out = (float*)d_out;                  // (512,256,6,7)  f32

    const int n_items = in_sizes[0] / 21;        // 131072
    const int grid = n_items / (NB * IPB);       // 512 = 2 blocks/CU exact
    canadarm_jacob_kernel<<<grid, 64, 0, stream>>>(com, pose, bm, out);
}